// Round 22
// baseline (309.142 us; speedup 1.0000x reference)
//
#include <hip/hip_runtime.h>
#include <hip/hip_bf16.h>

#define N_NODES 50000
#define N_EDGES 800000
#define DD 64
#define RPB 64
#define GBLOCKS ((N_NODES + RPB - 1) / RPB)       // 782
#define MBLOCKS ((N_NODES + 63) / 64)             // 782
#define NBUCKET ((N_NODES + 63) / 64)             // 782
#define PIDSTRIDE 800                             // ints per pid region (one-XCD owned)
#define NBP (NBUCKET * 8)                         // 6256 (bucket, xcd-partition) bins
#define EDGE_BLOCKS (N_EDGES / 256)               // 3125
#define BN_EPS 1e-5f

// ws layout (fp32 words), ~11.8 MB:
//   sumsA@0[128] sumsB@128[128] flags@256[2..pad 512]
//   bpcnt@512[6400 pid-major], off@6912[50064], boff@56976[800],
//   bpcur@57776[100096 line-padded], tmp32@157872[800000 u32],
//   srt[800000 u16], xb[3.2M bf16]
// Words [0 .. 6912) zeroed by hipMemsetAsync (sums + flags + bpcnt).
// d_out (fp32): O1 = h1 (fp32 self-term source), O2 = hpre scratch -> h2.

__device__ __forceinline__ float bf2f(unsigned short b) {
    return __uint_as_float(((unsigned)b) << 16);
}
__device__ __forceinline__ float loadF(const void* p, int i, int isf) {
    return isf ? ((const float*)p)[i] : bf2f(((const unsigned short*)p)[i]);
}
template<bool ISF>
__device__ __forceinline__ float4 ld4(const void* p, int i) {
    if (ISF) return *reinterpret_cast<const float4*>((const float*)p + i);
    ushort4 u = *reinterpret_cast<const ushort4*>((const unsigned short*)p + i);
    return make_float4(bf2f(u.x), bf2f(u.y), bf2f(u.z), bf2f(u.w));
}
// accumulate 8 bf16 (packed in uint4) into two float4s
__device__ __forceinline__ void acc8(float4& a, float4& b, uint4 u) {
    a.x += __uint_as_float(u.x << 16);
    a.y += __uint_as_float(u.x & 0xFFFF0000u);
    a.z += __uint_as_float(u.y << 16);
    a.w += __uint_as_float(u.y & 0xFFFF0000u);
    b.x += __uint_as_float(u.z << 16);
    b.y += __uint_as_float(u.z & 0xFFFF0000u);
    b.z += __uint_as_float(u.w << 16);
    b.w += __uint_as_float(u.w & 0xFFFF0000u);
}

// Merged: sniff (local per block), pid-major bucket hist (1 atomic/edge, one-XCD
// counter regions), cast x -> bf16 xb. No node histogram (R18's 40 MB write bug).
__global__ __launch_bounds__(256) void initcast_kernel(
    const void* __restrict__ x, const int* __restrict__ ei,
    int* __restrict__ flags, int* __restrict__ bpcnt,
    unsigned short* __restrict__ xb)
{
    __shared__ int cntF, cntI;
    int t = threadIdx.x;
    if (t == 0) { cntF = 0; cntI = 0; }
    __syncthreads();
    unsigned short wd = ((const unsigned short*)x)[2 * t];
    int e = (wd >> 7) & 0xFF;
    if (e >= 0x70 && e <= 0x8F) atomicAdd(&cntF, 1);        // bf16-plausible exponent
    if (t < 128 && ei[2 * t + 1] == 0) atomicAdd(&cntI, 1); // int64 high words are 0
    __syncthreads();
    int isf = (cntF < 128) ? 1 : 0;
    int i64 = (cntI > 64) ? 1 : 0;

    int gid = blockIdx.x * 256 + t;
    if (blockIdx.x == 0 && t == 0) {
        flags[0] = isf;
        flags[1] = i64;
    }

    {
        int d = i64 ? ei[2 * N_EDGES + 2 * gid] : ei[N_EDGES + gid];
        atomicAdd(bpcnt + (blockIdx.x & 7) * PIDSTRIDE + (d >> 6), 1);
    }

    int i = gid * 8;
    if (i < N_NODES * DD) {
        if (isf) {
            float4 a = *reinterpret_cast<const float4*>((const float*)x + i);
            float4 b = *reinterpret_cast<const float4*>((const float*)x + i + 4);
            ushort4 o0, o1;
            o0.x = __bfloat16_as_ushort(__float2bfloat16(a.x));
            o0.y = __bfloat16_as_ushort(__float2bfloat16(a.y));
            o0.z = __bfloat16_as_ushort(__float2bfloat16(a.z));
            o0.w = __bfloat16_as_ushort(__float2bfloat16(a.w));
            o1.x = __bfloat16_as_ushort(__float2bfloat16(b.x));
            o1.y = __bfloat16_as_ushort(__float2bfloat16(b.y));
            o1.z = __bfloat16_as_ushort(__float2bfloat16(b.z));
            o1.w = __bfloat16_as_ushort(__float2bfloat16(b.w));
            *reinterpret_cast<ushort4*>(xb + i) = o0;
            *reinterpret_cast<ushort4*>(xb + i + 4) = o1;
        } else {
            *reinterpret_cast<uint4*>(xb + i) =
                *reinterpret_cast<const uint4*>((const unsigned short*)x + i);
        }
    }
}

// single-block scan over (bucket-major, pid-minor) order reading pid-major bpcnt
// -> seeds line-padded bpcur + bucket starts boff[783].
#define BPCH 25  // 256*25 >= 6256
__global__ __launch_bounds__(256) void bpscan_kernel(const int* __restrict__ bpcnt,
                                                     int* __restrict__ bpcur,
                                                     int* __restrict__ boff) {
    __shared__ int tmp[256];
    int t = threadIdx.x;
    int lo = t * BPCH;
    int hi = lo + BPCH; if (hi > NBP) hi = NBP;
    int s = 0;
    for (int i = lo; i < hi; ++i)
        s += bpcnt[(i & 7) * PIDSTRIDE + (i >> 3)];
    tmp[t] = s;
    __syncthreads();
    #pragma unroll
    for (int d = 1; d < 256; d <<= 1) {
        int u = (t >= d) ? tmp[t - d] : 0;
        __syncthreads();
        tmp[t] += u;
        __syncthreads();
    }
    int run = (t == 0) ? 0 : tmp[t - 1];
    for (int i = lo; i < hi; ++i) {
        bpcur[i * 16] = run;
        if ((i & 7) == 0) boff[i >> 3] = run;
        run += bpcnt[(i & 7) * PIDSTRIDE + (i >> 3)];
    }
    if (t == 255) boff[NBUCKET] = tmp[255];
}

// fillA: scatter edges into their (bucket, blockIdx&7) sub-span — one XCD per
// sub-span's cache lines (R17-proven: 46 -> ~15 us).
__global__ void fillA_kernel(const int* __restrict__ ei, int* __restrict__ bpcur,
                             unsigned int* __restrict__ tmp, const int* __restrict__ flags) {
    int i64 = flags[1];
    int e = blockIdx.x * 256 + threadIdx.x;
    int s, d;
    if (i64) { s = ei[2 * e]; d = ei[2 * N_EDGES + 2 * e]; }
    else     { s = ei[e];     d = ei[N_EDGES + e]; }
    int bin = (d >> 6) * 8 + (blockIdx.x & 7);
    int pos = atomicAdd(bpcur + bin * 16, 1);
    tmp[pos] = (unsigned)s | ((unsigned)(d & 63) << 16);
}

// FUSED fillB + layer-1 gather+GEMM1+stats. One block per bucket, 512 threads.
// Phase A: derive per-node offsets (LDS hist + wave scan over tmp span), write
// off[] (for layer 2) and place srt (same-CU L2 write->read, coherent after
// __syncthreads vmcnt drain). Phase B: R13-frozen gather using LDS offsets.
__global__ __launch_bounds__(512) void gather1_fused_kernel(
    const unsigned short* __restrict__ xb, const void* __restrict__ self_src,
    const int* __restrict__ boff, const unsigned int* __restrict__ tmp,
    unsigned short* __restrict__ srt, int* __restrict__ off,
    const void* __restrict__ W, const void* __restrict__ bias,
    float* __restrict__ out_, float* __restrict__ sums, const int* __restrict__ flags)
{
    __shared__ float sIn[RPB][DD];            // 16 KB agg tile
    __shared__ float r1[8][DD], r2[8][DD];    // 4 KB stats (phase A aliases lcnt/cur)
    __shared__ int lofs[65];
    int tid = threadIdx.x;
    int lane = tid & 63, w = tid >> 6;
    int rs = lane >> 3, ch = lane & 7;
    int b = blockIdx.x;
    int row0 = b * RPB;
    int isf = flags[0];

    // ---- phase A: fillB for this bucket ----
    {
        int* lcnt = (int*)&r1[0][0];
        int* cur  = lcnt + 64;
        if (tid < 64) lcnt[tid] = 0;
        __syncthreads();
        int start = boff[b], end = boff[b + 1];
        for (int i = start + tid; i < end; i += 512)
            atomicAdd(&lcnt[tmp[i] >> 16], 1);
        __syncthreads();
        if (tid < 64) {
            int v = lcnt[tid];
            int s = v;
            #pragma unroll
            for (int d = 1; d < 64; d <<= 1) {
                int u = __shfl_up(s, d, 64);
                if (tid >= d) s += u;
            }
            int o = start + (s - v);            // exclusive
            int node = row0 + tid;
            if (node <= N_NODES) off[node] = o; // layer-2 gather reads this
            cur[tid] = o;
            lofs[tid] = o;
            if (tid == 63) lofs[64] = end;
        }
        __syncthreads();
        for (int i = start + tid; i < end; i += 512) {
            unsigned v = tmp[i];
            int pos = atomicAdd(&cur[v >> 16], 1);
            srt[pos] = (unsigned short)(v & 0xFFFFu);
        }
        __syncthreads();                        // vmcnt drain: srt visible to this CU
    }

    // ---- phase B: gather+GEMM1+stats (R13-frozen lane geometry) ----
    int lr = w * 8 + rs;
    int r = row0 + lr;
    float4 a  = make_float4(0.f, 0.f, 0.f, 0.f);
    float4 b4 = make_float4(0.f, 0.f, 0.f, 0.f);
    float4 a2 = make_float4(0.f, 0.f, 0.f, 0.f);
    float4 b2 = make_float4(0.f, 0.f, 0.f, 0.f);
    if (r < N_NODES) {
        a  = isf ? ld4<true>(self_src, r * DD + 8 * ch)
                 : ld4<false>(self_src, r * DD + 8 * ch);
        b4 = isf ? ld4<true>(self_src, r * DD + 8 * ch + 4)
                 : ld4<false>(self_src, r * DD + 8 * ch + 4);
        int k0 = lofs[lr], k1 = lofs[lr + 1];
        int k = k0;
        for (; k + 8 <= k1; k += 8) {
            int n0 = srt[k],     n1 = srt[k + 1], n2 = srt[k + 2], n3 = srt[k + 3];
            int n4 = srt[k + 4], n5 = srt[k + 5], n6 = srt[k + 6], n7 = srt[k + 7];
            uint4 u0 = *reinterpret_cast<const uint4*>(xb + n0 * DD + 8 * ch);
            uint4 u1 = *reinterpret_cast<const uint4*>(xb + n1 * DD + 8 * ch);
            uint4 u2 = *reinterpret_cast<const uint4*>(xb + n2 * DD + 8 * ch);
            uint4 u3 = *reinterpret_cast<const uint4*>(xb + n3 * DD + 8 * ch);
            uint4 u4 = *reinterpret_cast<const uint4*>(xb + n4 * DD + 8 * ch);
            uint4 u5 = *reinterpret_cast<const uint4*>(xb + n5 * DD + 8 * ch);
            uint4 u6 = *reinterpret_cast<const uint4*>(xb + n6 * DD + 8 * ch);
            uint4 u7 = *reinterpret_cast<const uint4*>(xb + n7 * DD + 8 * ch);
            acc8(a, b4, u0);
            acc8(a2, b2, u1);
            acc8(a, b4, u2);
            acc8(a2, b2, u3);
            acc8(a, b4, u4);
            acc8(a2, b2, u5);
            acc8(a, b4, u6);
            acc8(a2, b2, u7);
        }
        for (; k + 2 <= k1; k += 2) {
            int n0 = srt[k], n1 = srt[k + 1];
            uint4 u0 = *reinterpret_cast<const uint4*>(xb + n0 * DD + 8 * ch);
            uint4 u1 = *reinterpret_cast<const uint4*>(xb + n1 * DD + 8 * ch);
            acc8(a, b4, u0);
            acc8(a2, b2, u1);
        }
        if (k < k1) {
            int n0 = srt[k];
            acc8(a, b4, *reinterpret_cast<const uint4*>(xb + n0 * DD + 8 * ch));
        }
        a.x += a2.x; a.y += a2.y; a.z += a2.z; a.w += a2.w;
        b4.x += b2.x; b4.y += b2.y; b4.z += b2.z; b4.w += b2.w;
    }
    *reinterpret_cast<float4*>(&sIn[lr][8 * ch]) = a;
    *reinterpret_cast<float4*>(&sIn[lr][8 * ch + 4]) = b4;
    __syncthreads();

    float wcol[DD];
    #pragma unroll
    for (int k = 0; k < DD; ++k) wcol[k] = loadF(W, k * DD + lane, isf);
    float bv = loadF(bias, lane, isf);

    float s1 = 0.f, s2 = 0.f;
    #pragma unroll 4
    for (int j = 0; j < 8; ++j) {
        int jr = w * 8 + j;
        float c0 = 0.f, c1 = 0.f, c2 = 0.f, c3 = 0.f;
        #pragma unroll
        for (int k = 0; k < DD; k += 4) {
            float4 aa = *reinterpret_cast<const float4*>(&sIn[jr][k]);
            c0 += aa.x * wcol[k];
            c1 += aa.y * wcol[k + 1];
            c2 += aa.z * wcol[k + 2];
            c3 += aa.w * wcol[k + 3];
        }
        float acc = bv + ((c0 + c1) + (c2 + c3));
        int rr = row0 + jr;
        if (rr < N_NODES) {
            out_[rr * DD + lane] = acc;
            s1 += acc;
            s2 += acc * acc;
        }
    }
    r1[w][lane] = s1; r2[w][lane] = s2;
    __syncthreads();
    if (w == 0) {
        float t1 = 0.f, t2 = 0.f;
        #pragma unroll
        for (int q = 0; q < 8; ++q) { t1 += r1[q][lane]; t2 += r2[q][lane]; }
        atomicAdd(&sums[lane], t1);
        atomicAdd(&sums[64 + lane], t2);
    }
}

// layer-2 gather (R13-frozen), reading global off/srt written by gather1_fused.
__global__ __launch_bounds__(512) void gather_gemm_stats_kernel(
    const unsigned short* __restrict__ xb, const float* __restrict__ self_src,
    const int* __restrict__ off, const unsigned short* __restrict__ srt,
    const void* __restrict__ W, const void* __restrict__ bias,
    float* __restrict__ out_, float* __restrict__ sums, const int* __restrict__ flags)
{
    __shared__ float sIn[RPB][DD];
    __shared__ float r1[8][DD], r2[8][DD];
    int tid = threadIdx.x;
    int lane = tid & 63, w = tid >> 6;
    int rs = lane >> 3, ch = lane & 7;
    int row0 = blockIdx.x * RPB;
    int isf = flags[0];

    int lr = w * 8 + rs;
    int r = row0 + lr;
    float4 a  = make_float4(0.f, 0.f, 0.f, 0.f);
    float4 b  = make_float4(0.f, 0.f, 0.f, 0.f);
    float4 a2 = make_float4(0.f, 0.f, 0.f, 0.f);
    float4 b2 = make_float4(0.f, 0.f, 0.f, 0.f);
    if (r < N_NODES) {
        a = ld4<true>(self_src, r * DD + 8 * ch);
        b = ld4<true>(self_src, r * DD + 8 * ch + 4);
        int k0 = off[r], k1 = off[r + 1];
        int k = k0;
        for (; k + 8 <= k1; k += 8) {
            int n0 = srt[k],     n1 = srt[k + 1], n2 = srt[k + 2], n3 = srt[k + 3];
            int n4 = srt[k + 4], n5 = srt[k + 5], n6 = srt[k + 6], n7 = srt[k + 7];
            uint4 u0 = *reinterpret_cast<const uint4*>(xb + n0 * DD + 8 * ch);
            uint4 u1 = *reinterpret_cast<const uint4*>(xb + n1 * DD + 8 * ch);
            uint4 u2 = *reinterpret_cast<const uint4*>(xb + n2 * DD + 8 * ch);
            uint4 u3 = *reinterpret_cast<const uint4*>(xb + n3 * DD + 8 * ch);
            uint4 u4 = *reinterpret_cast<const uint4*>(xb + n4 * DD + 8 * ch);
            uint4 u5 = *reinterpret_cast<const uint4*>(xb + n5 * DD + 8 * ch);
            uint4 u6 = *reinterpret_cast<const uint4*>(xb + n6 * DD + 8 * ch);
            uint4 u7 = *reinterpret_cast<const uint4*>(xb + n7 * DD + 8 * ch);
            acc8(a, b, u0);
            acc8(a2, b2, u1);
            acc8(a, b, u2);
            acc8(a2, b2, u3);
            acc8(a, b, u4);
            acc8(a2, b2, u5);
            acc8(a, b, u6);
            acc8(a2, b2, u7);
        }
        for (; k + 2 <= k1; k += 2) {
            int n0 = srt[k], n1 = srt[k + 1];
            uint4 u0 = *reinterpret_cast<const uint4*>(xb + n0 * DD + 8 * ch);
            uint4 u1 = *reinterpret_cast<const uint4*>(xb + n1 * DD + 8 * ch);
            acc8(a, b, u0);
            acc8(a2, b2, u1);
        }
        if (k < k1) {
            int n0 = srt[k];
            acc8(a, b, *reinterpret_cast<const uint4*>(xb + n0 * DD + 8 * ch));
        }
        a.x += a2.x; a.y += a2.y; a.z += a2.z; a.w += a2.w;
        b.x += b2.x; b.y += b2.y; b.z += b2.z; b.w += b2.w;
    }
    *reinterpret_cast<float4*>(&sIn[lr][8 * ch]) = a;
    *reinterpret_cast<float4*>(&sIn[lr][8 * ch + 4]) = b;
    __syncthreads();

    float wcol[DD];
    #pragma unroll
    for (int k = 0; k < DD; ++k) wcol[k] = loadF(W, k * DD + lane, isf);
    float bv = loadF(bias, lane, isf);

    float s1 = 0.f, s2 = 0.f;
    #pragma unroll 4
    for (int j = 0; j < 8; ++j) {
        int jr = w * 8 + j;
        float c0 = 0.f, c1 = 0.f, c2 = 0.f, c3 = 0.f;
        #pragma unroll
        for (int k = 0; k < DD; k += 4) {
            float4 aa = *reinterpret_cast<const float4*>(&sIn[jr][k]);
            c0 += aa.x * wcol[k];
            c1 += aa.y * wcol[k + 1];
            c2 += aa.z * wcol[k + 2];
            c3 += aa.w * wcol[k + 3];
        }
        float acc = bv + ((c0 + c1) + (c2 + c3));
        int rr = row0 + jr;
        if (rr < N_NODES) {
            out_[rr * DD + lane] = acc;
            s1 += acc;
            s2 += acc * acc;
        }
    }
    r1[w][lane] = s1; r2[w][lane] = s2;
    __syncthreads();
    if (w == 0) {
        float t1 = 0.f, t2 = 0.f;
        #pragma unroll
        for (int q = 0; q < 8; ++q) { t1 += r1[q][lane]; t2 += r2[q][lane]; }
        atomicAdd(&sums[lane], t1);
        atomicAdd(&sums[64 + lane], t2);
    }
}

// h = relu(hpre*scale+shift); out = relu(h @ W2 + b2) -> fp32 (+ optional bf16 shadow).
// BN scale/shift computed inline from sums. In-place safe (LDS staged).
__global__ __launch_bounds__(256) void mlp2_kernel(
    const float* __restrict__ in_, const float* __restrict__ sums,
    const void* __restrict__ gma, const void* __restrict__ beta,
    const void* __restrict__ W, const void* __restrict__ bias,
    float* __restrict__ oF, unsigned short* obf, const int* __restrict__ flags)
{
    __shared__ float sIn[64][DD];
    __shared__ float sScale[DD], sShift[DD];
    int isf = flags[0];
    int tid = threadIdx.x;
    int c = tid & 63, g = tid >> 6;
    int row0 = blockIdx.x * 64;

    if (tid < 64) {
        float S1 = sums[tid];
        float S2 = sums[64 + tid];
        float mean = S1 * (1.0f / N_NODES);
        float var  = S2 * (1.0f / N_NODES) - mean * mean;
        float scale = rsqrtf(var + BN_EPS) * loadF(gma, tid, isf);
        sScale[tid] = scale;
        sShift[tid] = loadF(beta, tid, isf) - mean * scale;
    }
    __syncthreads();

    #pragma unroll
    for (int j = 0; j < 4; ++j) {
        int lr = (tid >> 4) + 16 * j;
        int cc = (tid & 15) << 2;
        int r = row0 + lr;
        float4 v = make_float4(0.f, 0.f, 0.f, 0.f);
        if (r < N_NODES) {
            v = *reinterpret_cast<const float4*>(in_ + r * DD + cc);
            float4 sc = *reinterpret_cast<const float4*>(&sScale[cc]);
            float4 sh = *reinterpret_cast<const float4*>(&sShift[cc]);
            v.x = fmaxf(v.x * sc.x + sh.x, 0.f);
            v.y = fmaxf(v.y * sc.y + sh.y, 0.f);
            v.z = fmaxf(v.z * sc.z + sh.z, 0.f);
            v.w = fmaxf(v.w * sc.w + sh.w, 0.f);
        }
        *reinterpret_cast<float4*>(&sIn[lr][cc]) = v;
    }
    __syncthreads();

    float wcol[DD];
    #pragma unroll
    for (int k = 0; k < DD; ++k) wcol[k] = loadF(W, k * DD + c, isf);
    float bv = loadF(bias, c, isf);

    #pragma unroll 4
    for (int j = 0; j < 16; ++j) {
        int lr = g * 16 + j;
        float a0 = 0.f, a1 = 0.f, a2 = 0.f, a3 = 0.f;
        #pragma unroll
        for (int k = 0; k < DD; k += 4) {
            float4 a = *reinterpret_cast<const float4*>(&sIn[lr][k]);
            a0 += a.x * wcol[k];
            a1 += a.y * wcol[k + 1];
            a2 += a.z * wcol[k + 2];
            a3 += a.w * wcol[k + 3];
        }
        float acc = fmaxf(bv + ((a0 + a1) + (a2 + a3)), 0.f);
        int r = row0 + lr;
        if (r < N_NODES) {
            oF[r * DD + c] = acc;
            if (obf) obf[r * DD + c] = __bfloat16_as_ushort(__float2bfloat16(acc));
        }
    }
}

extern "C" void kernel_launch(void* const* d_in, const int* in_sizes, int n_in,
                              void* d_out, int out_size, void* d_ws, size_t ws_size,
                              hipStream_t stream)
{
    (void)in_sizes; (void)n_in; (void)out_size; (void)ws_size;
    const void* x  = d_in[0];
    const int* ei  = (const int*)d_in[1];
    const void* W1_0 = d_in[2];  const void* b1_0 = d_in[3];
    const void* g_0  = d_in[4];  const void* be_0 = d_in[5];
    const void* W2_0 = d_in[6];  const void* b2_0 = d_in[7];
    const void* W1_1 = d_in[8];  const void* b1_1 = d_in[9];
    const void* g_1  = d_in[10]; const void* be_1 = d_in[11];
    const void* W2_1 = d_in[12]; const void* b2_1 = d_in[13];

    float* wsf   = (float*)d_ws;
    float* sumsA = wsf;                            // 128
    float* sumsB = wsf + 128;                      // 128
    int*  flags  = (int*)(wsf + 256);              // 2 (pad to 512)
    int*  bpcnt  = (int*)(wsf + 512);              // 6400 pid-major
    int*  off    = bpcnt + 6400;                   // 50064
    int*  boff   = off + 50064;                    // 800
    int*  bpcur  = boff + 800;                     // 100096 (line-padded)
    unsigned int* tmp32 = (unsigned int*)(bpcur + 100096);    // 800000 u32
    unsigned short* srt = (unsigned short*)(tmp32 + 800000);  // 800000 u16
    unsigned short* xb  = srt + 800064;                       // 3.2M bf16, 16B-aligned
    float* O1    = (float*)d_out;                  // h1 (fp32 self-term source)
    float* O2    = O1 + (size_t)N_NODES * DD;      // hpre scratch -> h2

    dim3 blk(256);

    // zero sums/flags/bpcnt, then bucket-CSR build + bf16 shadow
    hipMemsetAsync(d_ws, 0, (size_t)(512 + 6400) * 4, stream);
    initcast_kernel<<<EDGE_BLOCKS, blk, 0, stream>>>(x, ei, flags, bpcnt, xb);
    bpscan_kernel<<<1, blk, 0, stream>>>(bpcnt, bpcur, boff);
    fillA_kernel<<<EDGE_BLOCKS, blk, 0, stream>>>(ei, bpcur, tmp32, flags);

    // ---- layer 1 (fillB fused into gather) ----
    gather1_fused_kernel<<<NBUCKET, 512, 0, stream>>>(xb, x, boff, tmp32, srt, off,
                                                      W1_0, b1_0, O2, sumsA, flags);
    mlp2_kernel<<<MBLOCKS, blk, 0, stream>>>(O2, sumsA, g_0, be_0, W2_0, b2_0, O1, xb, flags);

    // ---- layer 2 ----
    gather_gemm_stats_kernel<<<GBLOCKS, 512, 0, stream>>>(xb, O1, off, srt, W1_1, b1_1,
                                                          O2, sumsB, flags);
    mlp2_kernel<<<MBLOCKS, blk, 0, stream>>>(O2, sumsB, g_1, be_1, W2_1, b2_1, O2, nullptr, flags);
}